// Round 1
// baseline (161.859 us; speedup 1.0000x reference)
//
#include <hip/hip_runtime.h>
#include <hip/hip_bf16.h>

#define N 4096
#define D 128
#define TILE 128
#define LDP 72   // 64 K-chunk + 8 bf16 pad (row stride 36 words -> 2-way max on b128, free)

typedef __attribute__((ext_vector_type(8))) short short8;
typedef __attribute__((ext_vector_type(4))) float f32x4;

// ---------------- kernel 0: cast to bf16, exact fp32 row norms, zero accumulators ----------------
__global__ __launch_bounds__(128) void k_prep(
    const float* __restrict__ X, const float* __restrict__ Y,
    __hip_bfloat16* __restrict__ Xb, __hip_bfloat16* __restrict__ Yb,
    float* __restrict__ xn, float* __restrict__ yn,
    float* __restrict__ R, float* __restrict__ TLr, float* __restrict__ sc)
{
    const int row = blockIdx.x, t = threadIdx.x;
    const float vx = X[row * D + t], vy = Y[row * D + t];
    Xb[row * D + t] = __float2bfloat16(vx);
    Yb[row * D + t] = __float2bfloat16(vy);
    float px = vx * vx, py = vy * vy;
#pragma unroll
    for (int m = 1; m < 64; m <<= 1) { px += __shfl_xor(px, m); py += __shfl_xor(py, m); }
    __shared__ float s[2][2];
    if ((t & 63) == 0) { s[t >> 6][0] = px; s[t >> 6][1] = py; }
    __syncthreads();
    if (t == 0) { xn[row] = s[0][0] + s[1][0]; yn[row] = s[0][1] + s[1][1]; }
    const int g = row * D + t;
    if (g < N) { R[g] = 0.f; TLr[g] = 0.f; }
    if (g < 16) sc[g] = 0.f;
}

// ---------------- matmul + fused epilogue; PASS=1 row sums, PASS=2 global sums ----------------
template <int PASS>
__global__ __launch_bounds__(256) void k_mat(
    const __hip_bfloat16* __restrict__ Yb, const __hip_bfloat16* __restrict__ Xb,
    const float* __restrict__ yn, const float* __restrict__ xn,
    float* __restrict__ pos, float* __restrict__ R, float* __restrict__ TLr,
    float* __restrict__ sc)
{
    __shared__ short ldsY[TILE * LDP];
    __shared__ short ldsX[TILE * LDP];
    __shared__ float ldsYn[TILE], ldsXn[TILE];
    __shared__ float rowA[TILE], rowB[TILE];   // PASS1: L/E row acc; PASS2: pos / exp(pos)
    __shared__ float wred[4][3];

    const int tid = threadIdx.x;
    const int bm = blockIdx.y, bn = blockIdx.x;
    const int row0 = bm * TILE, col0 = bn * TILE;
    const int lane = tid & 63, wave = tid >> 6;
    const int wm = (wave >> 1) * 64, wn = (wave & 1) * 64;
    const int l16 = lane & 15, quad = lane >> 4;

    if (tid < TILE) {
        ldsYn[tid] = yn[row0 + tid];
        ldsXn[tid] = xn[col0 + tid];
        if (PASS == 1) { rowA[tid] = 0.f; rowB[tid] = 0.f; }
        else { float p = pos[row0 + tid]; rowA[tid] = p; rowB[tid] = __expf(p); }
    }
    const float LB = (PASS == 2) ? sc[3] : 0.f;

    f32x4 acc[4][4];
#pragma unroll
    for (int a = 0; a < 4; a++)
#pragma unroll
        for (int b = 0; b < 4; b++) acc[a][b] = f32x4{0.f, 0.f, 0.f, 0.f};

#pragma unroll
    for (int ks = 0; ks < 2; ++ks) {
        if (ks) __syncthreads();
        const int4* gy = (const int4*)(Yb + (size_t)row0 * D + ks * 64);
        const int4* gx = (const int4*)(Xb + (size_t)col0 * D + ks * 64);
#pragma unroll
        for (int u = 0; u < 4; u++) {
            int e = tid + u * 256;
            int r = e >> 3, c = e & 7;
            *(int4*)&ldsY[r * LDP + c * 8] = gy[r * 16 + c];
            *(int4*)&ldsX[r * LDP + c * 8] = gx[r * 16 + c];
        }
        __syncthreads();
#pragma unroll
        for (int kk = 0; kk < 2; ++kk) {
            short8 af[4], bf[4];
#pragma unroll
            for (int t = 0; t < 4; t++) {
                af[t] = *(const short8*)&ldsY[(wm + t * 16 + l16) * LDP + kk * 32 + quad * 8];
                bf[t] = *(const short8*)&ldsX[(wn + t * 16 + l16) * LDP + kk * 32 + quad * 8];
            }
#pragma unroll
            for (int a = 0; a < 4; a++)
#pragma unroll
                for (int b = 0; b < 4; b++)
                    acc[a][b] = __builtin_amdgcn_mfma_f32_16x16x32_bf16(af[a], bf[b], acc[a][b], 0, 0, 0);
        }
    }

    if (PASS == 1) {
#pragma unroll
        for (int a = 0; a < 4; a++) {
#pragma unroll
            for (int r = 0; r < 4; r++) {
                const int gi = wm + a * 16 + quad * 4 + r;
                const float yv = ldsYn[gi];
                float sL = 0.f, sE = 0.f;
#pragma unroll
                for (int b = 0; b < 4; b++) {
                    const int gj = wn + b * 16 + l16;
                    float d = acc[a][b][r];
                    float s2 = fmaxf(yv + ldsXn[gj] - 2.f * d, 0.f);
                    float e = 1.f / (1.f + s2);         // == exp(L) exactly
                    float L = -__logf(1.f + s2);
                    sL += L; sE += e;
                    if (row0 + gi == col0 + gj) pos[row0 + gi] = L;
                }
#pragma unroll
                for (int m = 1; m < 16; m <<= 1) { sL += __shfl_xor(sL, m, 16); sE += __shfl_xor(sE, m, 16); }
                if (l16 == 0) { atomicAdd(&rowA[gi], sL); atomicAdd(&rowB[gi], sE); }
            }
        }
        __syncthreads();
        if (tid < TILE) {
            atomicAdd(&TLr[row0 + tid], rowA[tid]);
            atomicAdd(&R[row0 + tid], rowB[tid]);
        }
    } else {
        float sw = 0.f, sp = 0.f, sq = 0.f;
#pragma unroll
        for (int a = 0; a < 4; a++) {
#pragma unroll
            for (int r = 0; r < 4; r++) {
                const int gi = wm + a * 16 + quad * 4 + r;
                const float yv = ldsYn[gi];
                const float pv = rowA[gi], pe = rowB[gi];
#pragma unroll
                for (int b = 0; b < 4; b++) {
                    const int gj = wn + b * 16 + l16;
                    float d = acc[a][b][r];
                    float s2 = fmaxf(yv + ldsXn[gj] - 2.f * d, 0.f);
                    float e = 1.f / (1.f + s2);
                    float L = -__logf(1.f + s2);
                    float way = __logf(0.5f * (pe + e));
                    float a1 = pv + way - LB;
                    float a2 = way + L - LB;
                    sw += way;
                    sp += 1.f / (1.f + __expf(-a1));
                    sq += 1.f / (1.f + __expf(-a2));
                }
            }
        }
#pragma unroll
        for (int m = 1; m < 64; m <<= 1) { sw += __shfl_xor(sw, m); sp += __shfl_xor(sp, m); sq += __shfl_xor(sq, m); }
        if (lane == 0) { wred[wave][0] = sw; wred[wave][1] = sp; wred[wave][2] = sq; }
        __syncthreads();
        if (tid == 0) {
            float W = 0, P = 0, Q = 0;
            for (int w = 0; w < 4; w++) { W += wred[w][0]; P += wred[w][1]; Q += wred[w][2]; }
            atomicAdd(&sc[0], W); atomicAdd(&sc[1], P); atomicAdd(&sc[2], Q);
        }
    }
}

// ---------------- kernel 2: reduce rows -> LB, TP, diag corrections ----------------
__device__ __forceinline__ float block_sum(float v, float* sm)
{
#pragma unroll
    for (int m = 1; m < 64; m <<= 1) v += __shfl_xor(v, m);
    if ((threadIdx.x & 63) == 0) sm[threadIdx.x >> 6] = v;
    __syncthreads();
    float r = 0.f;
    if (threadIdx.x == 0) r = sm[0] + sm[1] + sm[2] + sm[3];
    __syncthreads();
    return r;  // valid on thread 0
}

__global__ __launch_bounds__(256) void k_mid(
    const float* __restrict__ pos, const float* __restrict__ R,
    const float* __restrict__ TLr, float* __restrict__ sc)
{
    __shared__ float sm[4];
    __shared__ float bc;
    const int tid = threadIdx.x;
    float sp = 0, sn = 0, tl = 0, ps = 0;
    for (int i = tid; i < N; i += 256) {
        float pv = pos[i], ep = __expf(pv);
        sp += ep; sn += R[i] - ep; tl += TLr[i] - pv; ps += pv;
    }
    sp = block_sum(sp, sm);
    sn = block_sum(sn, sm);
    tl = block_sum(tl, sm);
    ps = block_sum(ps, sm);
    if (tid == 0) {
        const float logM = __logf((float)N * (float)(N - 1));
        float lb2 = __logf(sn) - logM;
        float lb1 = __logf(0.5f * ((float)(N - 1) * sp + sn)) - logM;
        float LB = lb1 + lb2;
        sc[3] = LB; sc[4] = ps; sc[5] = tl;
        bc = LB;
    }
    __syncthreads();
    const float LB = bc;
    float tp = 0, sgd = 0;
    for (int i = tid; i < N; i += 256) {
        float pv = pos[i], ep = __expf(pv);
        float Roff = R[i] - ep;
        float pf = pv - LB + __logf(0.5f * ((float)(N - 1) * ep + Roff)) - __logf((float)(N - 1));
        tp += 1.f / (1.f + __expf(-pf));
        sgd += 1.f / (1.f + __expf(-(2.f * pv - LB)));
    }
    tp = block_sum(tp, sm);
    sgd = block_sum(sgd, sm);
    if (tid == 0) { sc[6] = tp / (float)N; sc[7] = sgd; }
}

// ---------------- kernel 4: finalize 9 outputs ----------------
__global__ void k_fin(const float* __restrict__ sc, float* __restrict__ out)
{
    if (threadIdx.x == 0 && blockIdx.x == 0) {
        const float M = (float)N * (float)(N - 1);
        float W   = sc[0] - sc[4];   // subtract diagonal (way_ii == pos_i)
        float SGP = sc[1] - sc[7];
        float SGN = sc[2] - sc[7];
        float LB = sc[3], Sp = sc[4], TL = sc[5], TP = sc[6];
        float o0 = Sp / (float)N + W / M - LB;
        float o1 = W / M + TL / M - LB;
        float o2 = SGP / M, o3 = SGN / M;
        float FP = o3;
        out[0] = o0;
        out[1] = o1;
        out[2] = o2;
        out[3] = o3;
        out[4] = (TP + (1.f - FP)) * 0.5f;
        out[5] = TP;
        out[6] = TP / (TP + FP);
        out[7] = LB;
        out[8] = -o0 + 2.0f;   // gatt.mean + grep.mean (== 2 exactly) + 0 decay
    }
}

extern "C" void kernel_launch(void* const* d_in, const int* in_sizes, int n_in,
                              void* d_out, int out_size, void* d_ws, size_t ws_size,
                              hipStream_t stream)
{
    const float* X = (const float*)d_in[0];  // z_x  (columns of logits)
    const float* Y = (const float*)d_in[1];  // z_y  (rows of logits)
    float* out = (float*)d_out;

    char* ws = (char*)d_ws;
    __hip_bfloat16* Yb = (__hip_bfloat16*)(ws);                 // 1 MB
    __hip_bfloat16* Xb = (__hip_bfloat16*)(ws + (1 << 20));     // 1 MB
    float* yn  = (float*)(ws + (2 << 20));
    float* xn  = yn + N;
    float* pos = xn + N;
    float* R   = pos + N;
    float* TLr = R + N;
    float* sc  = TLr + N;   // 16 floats of scalars

    k_prep<<<N, 128, 0, stream>>>(X, Y, Xb, Yb, xn, yn, R, TLr, sc);
    k_mat<1><<<dim3(N / TILE, N / TILE), 256, 0, stream>>>(Yb, Xb, yn, xn, pos, R, TLr, sc);
    k_mid<<<1, 256, 0, stream>>>(pos, R, TLr, sc);
    k_mat<2><<<dim3(N / TILE, N / TILE), 256, 0, stream>>>(Yb, Xb, yn, xn, pos, R, TLr, sc);
    k_fin<<<1, 64, 0, stream>>>(sc, out);
}

// Round 2
// 133.947 us; speedup vs baseline: 1.2084x; 1.2084x over previous
//
#include <hip/hip_runtime.h>
#include <hip/hip_bf16.h>

#define N 4096
#define D 128
#define TILE 128
#define LDP 72   // 64 K-chunk + 8 bf16 pad

typedef __attribute__((ext_vector_type(8))) short short8;
typedef __attribute__((ext_vector_type(4))) float f32x4;

#define LOG2E 1.44269504088896340736f
#define LN2   0.69314718055994530942f

#if __has_builtin(__builtin_amdgcn_rcpf)
__device__ __forceinline__ float fast_rcp(float x) { return __builtin_amdgcn_rcpf(x); }
#else
__device__ __forceinline__ float fast_rcp(float x) { return 1.f / x; }
#endif
#if __has_builtin(__builtin_amdgcn_logf)
__device__ __forceinline__ float fast_log2(float x) { return __builtin_amdgcn_logf(x); }
#else
__device__ __forceinline__ float fast_log2(float x) { return __log2f(x); }
#endif
#if __has_builtin(__builtin_amdgcn_exp2f)
__device__ __forceinline__ float fast_exp2(float x) { return __builtin_amdgcn_exp2f(x); }
#else
__device__ __forceinline__ float fast_exp2(float x) { return exp2f(x); }
#endif

// sigmoid(x) given nl2 = -x*log2(e):  1/(1+2^nl2)
__device__ __forceinline__ float sig_nl2(float nl2) {
    return fast_rcp(1.f + fast_exp2(nl2));
}

// ---------------- kernel 0: cast to bf16, exact fp32 row norms, zero accumulators ----------------
__global__ __launch_bounds__(128) void k_prep(
    const float* __restrict__ X, const float* __restrict__ Y,
    __hip_bfloat16* __restrict__ Xb, __hip_bfloat16* __restrict__ Yb,
    float* __restrict__ xn, float* __restrict__ yn,
    float* __restrict__ R, float* __restrict__ TLr, float* __restrict__ sc)
{
    const int row = blockIdx.x, t = threadIdx.x;
    const float vx = X[row * D + t], vy = Y[row * D + t];
    Xb[row * D + t] = __float2bfloat16(vx);
    Yb[row * D + t] = __float2bfloat16(vy);
    float px = vx * vx, py = vy * vy;
#pragma unroll
    for (int m = 1; m < 64; m <<= 1) { px += __shfl_xor(px, m); py += __shfl_xor(py, m); }
    __shared__ float s[2][2];
    if ((t & 63) == 0) { s[t >> 6][0] = px; s[t >> 6][1] = py; }
    __syncthreads();
    if (t == 0) { xn[row] = s[0][0] + s[1][0]; yn[row] = s[0][1] + s[1][1]; }
    const int g = row * D + t;
    if (g < N) { R[g] = 0.f; TLr[g] = 0.f; }
    if (g < 16) sc[g] = 0.f;
}

// ---------------- matmul (transposed: j on C-rows, i on C-cols) + fused epilogue ----------------
// PASS=1: row sums of log2(1+s2) and 1/(1+s2)  (log2 units for L)
// PASS=2: global sums of way-log2, sigmoid(pos-part), sigmoid(neg-part)
template <int PASS>
__global__ __launch_bounds__(256) void k_mat(
    const __hip_bfloat16* __restrict__ Yb, const __hip_bfloat16* __restrict__ Xb,
    const float* __restrict__ yn, const float* __restrict__ xn,
    float* __restrict__ pos, float* __restrict__ R, float* __restrict__ TLr,
    float* __restrict__ sc)
{
    __shared__ short ldsY[TILE * LDP];
    __shared__ short ldsX[TILE * LDP];
    __shared__ __align__(16) float ldsYn[TILE];
    __shared__ __align__(16) float ldsXn[TILE];
    __shared__ float rowA[TILE], rowB[TILE];   // PASS1: log2L/E row acc; PASS2: pos / exp(pos)
    __shared__ float wred[4][3];

    const int tid = threadIdx.x;
    const int bm = blockIdx.y, bn = blockIdx.x;
    const int row0 = bm * TILE, col0 = bn * TILE;   // row0 -> i (Y), col0 -> j (X)
    const int lane = tid & 63, wave = tid >> 6;
    const int wj = (wave >> 1) * 64;   // j offset within tile (C rows)
    const int wi = (wave & 1) * 64;    // i offset within tile (C cols)
    const int l16 = lane & 15, quad = lane >> 4;

    if (tid < TILE) {
        ldsYn[tid] = yn[row0 + tid];
        ldsXn[tid] = xn[col0 + tid];
        if (PASS == 1) { rowA[tid] = 0.f; rowB[tid] = 0.f; }
        else { float p = pos[row0 + tid]; rowA[tid] = p; rowB[tid] = fast_exp2(p * LOG2E); }
    }
    const float LB = (PASS == 2) ? sc[3] : 0.f;

    f32x4 acc[4][4];
#pragma unroll
    for (int a = 0; a < 4; a++)
#pragma unroll
        for (int b = 0; b < 4; b++) acc[a][b] = f32x4{0.f, 0.f, 0.f, 0.f};

#pragma unroll
    for (int ks = 0; ks < 2; ++ks) {
        if (ks) __syncthreads();
        const int4* gy = (const int4*)(Yb + (size_t)row0 * D + ks * 64);
        const int4* gx = (const int4*)(Xb + (size_t)col0 * D + ks * 64);
#pragma unroll
        for (int u = 0; u < 4; u++) {
            int e = tid + u * 256;
            int r = e >> 3, c = e & 7;
            *(int4*)&ldsY[r * LDP + c * 8] = gy[r * 16 + c];
            *(int4*)&ldsX[r * LDP + c * 8] = gx[r * 16 + c];
        }
        __syncthreads();
#pragma unroll
        for (int kk = 0; kk < 2; ++kk) {
            short8 af[4], bf[4];
#pragma unroll
            for (int t = 0; t < 4; t++) {
                af[t] = *(const short8*)&ldsX[(wj + t * 16 + l16) * LDP + kk * 32 + quad * 8];
                bf[t] = *(const short8*)&ldsY[(wi + t * 16 + l16) * LDP + kk * 32 + quad * 8];
            }
#pragma unroll
            for (int a = 0; a < 4; a++)
#pragma unroll
                for (int b = 0; b < 4; b++)
                    acc[a][b] = __builtin_amdgcn_mfma_f32_16x16x32_bf16(af[a], bf[b], acc[a][b], 0, 0, 0);
        }
    }
    // acc[a][b][r] = dot(y_i, x_j) with j = wj + a*16 + quad*4 + r (local), i = wi + b*16 + l16 (local)

    if (PASS == 1) {
        float sL[4] = {0.f, 0.f, 0.f, 0.f}, sE[4] = {0.f, 0.f, 0.f, 0.f};
        const bool diag = (row0 == col0);
#pragma unroll
        for (int a = 0; a < 4; a++) {
            const int jl = wj + a * 16 + quad * 4;
            const f32x4 xnv = *(const f32x4*)&ldsXn[jl];
#pragma unroll
            for (int b = 0; b < 4; b++) {
                const int il = wi + b * 16 + l16;
                const float ynv = ldsYn[il];
#pragma unroll
                for (int r = 0; r < 4; r++) {
                    float s2 = fmaxf(ynv + xnv[r] - 2.f * acc[a][b][r], 0.f);
                    float t = 1.f + s2;
                    float lg = fast_log2(t);           // -L in log2 units
                    sL[b] += lg;
                    sE[b] += fast_rcp(t);              // exp(L)
                    if (diag && il == jl + r) pos[row0 + il] = -LN2 * lg;
                }
            }
        }
#pragma unroll
        for (int b = 0; b < 4; b++) {
            sL[b] += __shfl_xor(sL[b], 16); sL[b] += __shfl_xor(sL[b], 32);
            sE[b] += __shfl_xor(sE[b], 16); sE[b] += __shfl_xor(sE[b], 32);
            if (lane < 16) {
                atomicAdd(&rowA[wi + b * 16 + l16], sL[b]);
                atomicAdd(&rowB[wi + b * 16 + l16], sE[b]);
            }
        }
        __syncthreads();
        if (tid < TILE) {
            atomicAdd(&TLr[row0 + tid], rowA[tid]);   // sum_j log2(1+s2)  (incl. diagonal)
            atomicAdd(&R[row0 + tid], rowB[tid]);     // sum_j exp(L)      (incl. diagonal)
        }
    } else {
        const float LB2c = LB * LOG2E + 1.f;
        float sw = 0.f, sp = 0.f, sq = 0.f;
#pragma unroll
        for (int b = 0; b < 4; b++) {
            const int il = wi + b * 16 + l16;
            const float ynv = ldsYn[il];
            const float pe  = rowB[il];
            const float c1n = 1.f - (rowA[il] - LB) * LOG2E;
#pragma unroll
            for (int a = 0; a < 4; a++) {
                const f32x4 xnv = *(const f32x4*)&ldsXn[wj + a * 16 + quad * 4];
#pragma unroll
                for (int r = 0; r < 4; r++) {
                    float s2 = fmaxf(ynv + xnv[r] - 2.f * acc[a][b][r], 0.f);
                    float t = 1.f + s2;
                    float lg2t  = fast_log2(t);            // = -L*log2e
                    float e     = fast_rcp(t);             // exp(L)
                    float lg2pe = fast_log2(pe + e);       // way*log2e + 1
                    sw += lg2pe;
                    sp += sig_nl2(c1n - lg2pe);            // sigmoid(pos + way - LB)
                    sq += sig_nl2(LB2c - lg2pe + lg2t);    // sigmoid(way + L - LB)
                }
            }
        }
#pragma unroll
        for (int m = 1; m < 64; m <<= 1) { sw += __shfl_xor(sw, m); sp += __shfl_xor(sp, m); sq += __shfl_xor(sq, m); }
        if (lane == 0) { wred[wave][0] = sw; wred[wave][1] = sp; wred[wave][2] = sq; }
        __syncthreads();
        if (tid == 0) {
            float W = 0, P = 0, Q = 0;
            for (int w = 0; w < 4; w++) { W += wred[w][0]; P += wred[w][1]; Q += wred[w][2]; }
            atomicAdd(&sc[0], W); atomicAdd(&sc[1], P); atomicAdd(&sc[2], Q);
        }
    }
}

// ---------------- kernel 2: reduce rows -> LB, TP, diag corrections ----------------
__device__ __forceinline__ float block_sum(float v, float* sm)
{
#pragma unroll
    for (int m = 1; m < 64; m <<= 1) v += __shfl_xor(v, m);
    if ((threadIdx.x & 63) == 0) sm[threadIdx.x >> 6] = v;
    __syncthreads();
    float r = 0.f;
    if (threadIdx.x == 0) r = sm[0] + sm[1] + sm[2] + sm[3];
    __syncthreads();
    return r;  // valid on thread 0
}

__global__ __launch_bounds__(256) void k_mid(
    const float* __restrict__ pos, const float* __restrict__ R,
    const float* __restrict__ TLr, float* __restrict__ sc)
{
    __shared__ float sm[4];
    __shared__ float bc;
    const int tid = threadIdx.x;
    float sp = 0, sn = 0, tl = 0, ps = 0;
    for (int i = tid; i < N; i += 256) {
        float pv = pos[i], ep = fast_exp2(pv * LOG2E);
        sp += ep; sn += R[i] - ep;
        tl += -LN2 * TLr[i] - pv;   // sum_{j!=i} L_ij  (TLr is log2 of all j incl diag)
        ps += pv;
    }
    sp = block_sum(sp, sm);
    sn = block_sum(sn, sm);
    tl = block_sum(tl, sm);
    ps = block_sum(ps, sm);
    if (tid == 0) {
        const float logM = __logf((float)N * (float)(N - 1));
        float lb2 = __logf(sn) - logM;
        float lb1 = __logf(0.5f * ((float)(N - 1) * sp + sn)) - logM;
        float LB = lb1 + lb2;
        sc[3] = LB; sc[4] = ps; sc[5] = tl;
        bc = LB;
    }
    __syncthreads();
    const float LB = bc;
    float tp = 0, sgd = 0;
    for (int i = tid; i < N; i += 256) {
        float pv = pos[i], ep = fast_exp2(pv * LOG2E);
        float Roff = R[i] - ep;
        float pf = pv - LB + __logf(0.5f * ((float)(N - 1) * ep + Roff)) - __logf((float)(N - 1));
        tp += sig_nl2(-pf * LOG2E);
        sgd += sig_nl2(-(2.f * pv - LB) * LOG2E);
    }
    tp = block_sum(tp, sm);
    sgd = block_sum(sgd, sm);
    if (tid == 0) { sc[6] = tp / (float)N; sc[7] = sgd; }
}

// ---------------- kernel 4: finalize 9 outputs ----------------
__global__ void k_fin(const float* __restrict__ sc, float* __restrict__ out)
{
    if (threadIdx.x == 0 && blockIdx.x == 0) {
        const float M = (float)N * (float)(N - 1);
        // sc[0] = sum_ij lg2pe = sum_ij (way*log2e + 1)  ->  sum way(ln) = LN2*(sc[0] - N*N)
        float W   = LN2 * (sc[0] - (float)N * (float)N) - sc[4];  // off-diagonal sum of way
        float SGP = sc[1] - sc[7];
        float SGN = sc[2] - sc[7];
        float LB = sc[3], Sp = sc[4], TL = sc[5], TP = sc[6];
        float o0 = Sp / (float)N + W / M - LB;
        float o1 = W / M + TL / M - LB;
        float o2 = SGP / M, o3 = SGN / M;
        float FP = o3;
        out[0] = o0;
        out[1] = o1;
        out[2] = o2;
        out[3] = o3;
        out[4] = (TP + (1.f - FP)) * 0.5f;
        out[5] = TP;
        out[6] = TP / (TP + FP);
        out[7] = LB;
        out[8] = -o0 + 2.0f;   // gatt.mean + grep.mean (== 2 exactly) + 0 decay
    }
}

extern "C" void kernel_launch(void* const* d_in, const int* in_sizes, int n_in,
                              void* d_out, int out_size, void* d_ws, size_t ws_size,
                              hipStream_t stream)
{
    const float* X = (const float*)d_in[0];  // z_x  (columns of logits)
    const float* Y = (const float*)d_in[1];  // z_y  (rows of logits)
    float* out = (float*)d_out;

    char* ws = (char*)d_ws;
    __hip_bfloat16* Yb = (__hip_bfloat16*)(ws);                 // 1 MB
    __hip_bfloat16* Xb = (__hip_bfloat16*)(ws + (1 << 20));     // 1 MB
    float* yn  = (float*)(ws + (2 << 20));
    float* xn  = yn + N;
    float* pos = xn + N;
    float* R   = pos + N;
    float* TLr = R + N;
    float* sc  = TLr + N;   // 16 floats of scalars

    k_prep<<<N, 128, 0, stream>>>(X, Y, Xb, Yb, xn, yn, R, TLr, sc);
    k_mat<1><<<dim3(N / TILE, N / TILE), 256, 0, stream>>>(Yb, Xb, yn, xn, pos, R, TLr, sc);
    k_mid<<<1, 256, 0, stream>>>(pos, R, TLr, sc);
    k_mat<2><<<dim3(N / TILE, N / TILE), 256, 0, stream>>>(Yb, Xb, yn, xn, pos, R, TLr, sc);
    k_fin<<<1, 64, 0, stream>>>(sc, out);
}